// Round 1
// baseline (963.810 us; speedup 1.0000x reference)
//
#include <hip/hip_runtime.h>

#define RES 1024
#define SEQ 512

typedef _Float16 f16;
typedef _Float16 half8 __attribute__((ext_vector_type(8)));
typedef float f32x4 __attribute__((ext_vector_type(4)));
typedef float f32x2 __attribute__((ext_vector_type(2), aligned(4)));
typedef unsigned int uint4v __attribute__((ext_vector_type(4)));
typedef unsigned int uint2v __attribute__((ext_vector_type(2)));

// LDS partial-sum layout [w8][n][r][c], odd row-stride 19 (round-5): both the
// MFMA partial-write set and the reduce-read set are exact 2-way (free, m136).
#define PSZ (8 * 4 * 16 * 19)
#define PIDX(w8, n, rr, cc) ((((w8) * 4 + (n)) * 16 + (rr)) * 19 + (cc))

// Workspace layout (memset 0 each launch):
//   [0   , 512K) : PRIMARY H buffer 0   (plain write-back stores -> local XCD L2)
//   [512K, 1M  ) : PRIMARY H buffer 1
//   [1M  , 1.5M) : MIRROR  H buffer 0   (write-through agent stores; ONLY used
//   [1.5M, 2M  ) : MIRROR  H buffer 1    by groups that fail the placement check)
//   [2M  , 2M+1K)    : xcdmap, uint[256]
//   [2M+1K, 2M+2K)   : flags, uint[16 groups][16 wgs] (monotonic step counters)
//
// Grid: 256 wgs x 512 threads. wg -> (group g, slice w):
//   g = (bx&7)*2 + ((bx>>3)&1), w = bx>>4   (a group's 16 wgs share bx mod 16)
// Group g owns batch rows [g*16,g*16+16); wg w owns reservoir cols [w*64,w*64+64).
// Wave k consumes K-range [k*128,(k+1)*128) -> producers {2k,2k+1}.
//
// Round-15 = round-14 champion with ONE protocol change: cheap retries.
// Theory: the dominant per-step cost is L2->CU delivery inflated by the spin
// protocol — every failed tag check re-fetches the FULL 4KB/wave A tile, and
// with the group phase-locked the first attempt usually races the producers'
// stores, so effective delivery is ~(1+retries)x32KB/CU/step and the extra L2
// pressure amplifies itself. Fix: keep the tagged-data FIRST attempt (optimal
// latency when data already landed), but on a miss spin on an 8-byte per-wave
// progress-flag pair (monotonic step counters, one dwordx2 covering producers
// {2k,2k+1}) and then load the data exactly once. Release ordering is free:
// barrier-2's __syncthreads() drains vmcnt(0) for all the wg's h-stores BEFORE
// tid 0 stores the flag, so flag >= s  ==>  h_s fully visible in the local L2.
// Flags are plain write-back stores (stay in the group's own XCD L2 line);
// only l2mode groups consult them — fallback groups keep the round-6 mirror
// protocol byte-for-byte. Monotonic counters cannot false-positive; the tag
// check is kept as a backstop after the flag-confirmed load.

__device__ __forceinline__ float fast_tanh(float v) {
  float vc = fminf(15.0f, fmaxf(-15.0f, v));
  float e = __expf(2.0f * vc);
  return (e - 1.0f) * __builtin_amdgcn_rcpf(e + 1.0f);
}

#define FULL_LOAD(ptr)                                                  \
  asm volatile(                                                         \
      "global_load_dwordx4 %0, %4, off sc0 sc1\n\t"                     \
      "global_load_dwordx4 %1, %4, off offset:64 sc0 sc1\n\t"           \
      "global_load_dwordx4 %2, %4, off offset:128 sc0 sc1\n\t"          \
      "global_load_dwordx4 %3, %4, off offset:192 sc0 sc1\n\t"          \
      "s_waitcnt vmcnt(0)"                                              \
      : "=&v"(A0), "=&v"(A1), "=&v"(A2), "=&v"(A3) : "v"(ptr) : "memory")

__device__ __forceinline__ bool tags_ok(half8 A0, half8 A1, half8 A2, half8 A3,
                                        unsigned int tagr) {
  const uint4v b0 = __builtin_bit_cast(uint4v, A0);
  const uint4v b1 = __builtin_bit_cast(uint4v, A1);
  const uint4v b2 = __builtin_bit_cast(uint4v, A2);
  const uint4v b3 = __builtin_bit_cast(uint4v, A3);
  unsigned int d =
      (b0.x ^ tagr) | (b0.y ^ tagr) | (b0.z ^ tagr) | (b0.w ^ tagr) |
      (b1.x ^ tagr) | (b1.y ^ tagr) | (b1.z ^ tagr) | (b1.w ^ tagr) |
      (b2.x ^ tagr) | (b2.y ^ tagr) | (b2.z ^ tagr) | (b2.w ^ tagr) |
      (b3.x ^ tagr) | (b3.y ^ tagr) | (b3.z ^ tagr) | (b3.w ^ tagr);
  return ((d & 1u) == 0u);
}

__global__ __launch_bounds__(512, 2) void res_recur_kernel(
    const float* __restrict__ x,      // [256][512]
    const float* __restrict__ W_in,   // [1024]
    const float* __restrict__ W_res,  // [1024][1024]
    f16* __restrict__ hp0,            // primary buffers
    f16* __restrict__ hp1,
    f16* __restrict__ hm0,            // mirror buffers (fallback groups only)
    f16* __restrict__ hm1,
    unsigned int* __restrict__ xcdmap,
    unsigned int* __restrict__ flags) // [16][16] monotonic progress counters
{
  // [2][PSZ+1024] = 86,016 B total: > 80 KB forces 1 wg/CU (the round-14 lever).
  // Only plane [0] is used; the second plane exists purely as LDS ballast that
  // the compiler cannot strip (single allocated object, dynamically indexed).
  __shared__ float P[2][PSZ + 1024];
  __shared__ unsigned char xmap_s[256];
  __shared__ int l2mode_s;

  const int tid  = threadIdx.x;
  const int wave = tid >> 6;
  const int lane = tid & 63;
  const int col  = lane & 15;
  const int kq   = (lane >> 4) & 3;

  const int bx = blockIdx.x;
  const int g  = (bx & 7) * 2 + ((bx >> 3) & 1);
  const int w  = bx >> 4;

  // ---- publish my XCC id (write-through agent store -> globally visible)
  unsigned int myxcc;
  asm volatile("s_getreg_b32 %0, hwreg(HW_REG_XCC_ID, 0, 8)" : "=s"(myxcc));
  if (tid == 0)
    __hip_atomic_store(&xcdmap[bx], (myxcc & 0xffu) + 1u, __ATOMIC_RELAXED,
                       __HIP_MEMORY_SCOPE_AGENT);

  // ---- W_res fragments (MFMA B operand), register-resident for the whole run.
  // Wf[n][ks] elem j = W_res[w*64+n*16+col][ wave*128 + ks*32 + kq*8 + j ]
  half8 Wf[4][4];
#pragma unroll
  for (int n = 0; n < 4; ++n) {
    const float* Wr = W_res + (size_t)(w * 64 + n * 16 + col) * RES + wave * 128 + kq * 8;
#pragma unroll
    for (int ks = 0; ks < 4; ++ks) {
      f32x4 lo = *(const f32x4*)(Wr + ks * 32);
      f32x4 hi = *(const f32x4*)(Wr + ks * 32 + 4);
      half8 f;
#pragma unroll
      for (int j = 0; j < 4; ++j) { f[j] = (f16)lo[j]; f[j + 4] = (f16)hi[j]; }
      Wf[n][ks] = f;
    }
  }

  // ---- gather all 256 XCC ids (coherent sc0 sc1 loads; 256 wgs on 256 CUs are
  // trivially co-resident at 1 wg/CU, so this terminates)
  if (tid < 256) {
    const unsigned int* ap = xcdmap + tid;
    unsigned int v;
    do {
      asm volatile("global_load_dword %0, %1, off sc0 sc1\n\t"
                   "s_waitcnt vmcnt(0)"
                   : "=&v"(v) : "v"(ap) : "memory");
    } while (v == 0u);
    xmap_s[tid] = (unsigned char)v;
  }
  __syncthreads();
  if (tid == 0) {
    const int base = (g >> 1) + 8 * (g & 1);   // bx of this group's w=0 member
    const unsigned char ref = xmap_s[base];
    int ok = 1, cnt = 0;
    for (int i = 0; i < 256; ++i) cnt += (xmap_s[i] == ref) ? 1 : 0;
    for (int k = 0; k < 16; ++k) ok &= (xmap_s[base + 16 * k] == ref) ? 1 : 0;
    l2mode_s = (ok && cnt <= 64) ? 1 : 0;
  }
  __syncthreads();
  const bool l2mode = (l2mode_s != 0);   // group-uniform by construction

  // ---- epilogue assignment: thread t -> (batch-row r, col pair) of the 16x64 tile
  const int r   = tid >> 5;            // 0..15
  const int cp  = tid & 31;            // col pair
  const int n_e = cp >> 3;             // n-tile 0..3
  const int c0  = (cp & 7) * 2;        // even col within tile
  const float win_lo = W_in[w * 64 + n_e * 16 + c0];
  const float win_hi = W_in[w * 64 + n_e * 16 + c0 + 1];
  const float* xr = x + (size_t)(g * 16 + r) * SEQ;
  const unsigned int houtidx = ((unsigned)(g * 16 + r) * RES + w * 64 + n_e * 16 + c0) >> 1;

  const size_t aoff = (size_t)(g * 16 + col) * RES + wave * 128 + kq * 8;
  const unsigned int* fpair = flags + (g * 16 + wave * 2);  // producers {2k,2k+1}
  unsigned int* fmine = flags + (g * 16 + w);

  for (int s = 0; s < SEQ; ++s) {
    const unsigned int su = (unsigned int)s;
    float u = xr[s];

    f32x4 acc[4];
#pragma unroll
    for (int n = 0; n < 4; ++n) acc[n] = (f32x4){0.f, 0.f, 0.f, 0.f};

    if (s > 0) {
      const unsigned int tagr = (unsigned)(((s >> 1) + (s & 1)) & 1);
      const f16* Ap = ((s & 1) ? hp1 : hp0) + aoff;   // primary (same-XCD L2)
      const f16* Am = ((s & 1) ? hm1 : hm0) + aoff;   // mirror  (fallback)
      half8 A0, A1, A2, A3;

      // attempt 0: direct data load + tag check (optimal-latency fast path)
      FULL_LOAD(Ap);
      bool ok = tags_ok(A0, A1, A2, A3, tagr);
      if (!ok) {
        if (l2mode) {
          // cheap spin: poll the two producers' 8-byte flag pair until both
          // have published step s, then fetch the data exactly once.
          for (;;) {
            uint2v f;
            asm volatile("global_load_dwordx2 %0, %1, off sc0 sc1\n\t"
                         "s_waitcnt vmcnt(0)"
                         : "=&v"(f) : "v"(fpair) : "memory");
            if (f.x >= su && f.y >= su) break;
          }
          // flag >= s ==> producers' h_s stores drained (barrier-2) => valid.
          // Tag check retained as a backstop only.
          do {
            FULL_LOAD(Ap);
          } while (!tags_ok(A0, A1, A2, A3, tagr));
        } else {
          // unverified group: round-6 protocol, every-8th-retry LLC fallback
          unsigned int it = 0;
          do {
            ++it;
            const f16* Pp = ((it & 7u) == 0u) ? Am : Ap;
            FULL_LOAD(Pp);
          } while (!tags_ok(A0, A1, A2, A3, tagr));
        }
      }

#pragma unroll
      for (int n = 0; n < 4; ++n) acc[n] = __builtin_amdgcn_mfma_f32_16x16x32_f16(A0, Wf[n][0], acc[n], 0, 0, 0);
#pragma unroll
      for (int n = 0; n < 4; ++n) acc[n] = __builtin_amdgcn_mfma_f32_16x16x32_f16(A1, Wf[n][1], acc[n], 0, 0, 0);
#pragma unroll
      for (int n = 0; n < 4; ++n) acc[n] = __builtin_amdgcn_mfma_f32_16x16x32_f16(A2, Wf[n][2], acc[n], 0, 0, 0);
#pragma unroll
      for (int n = 0; n < 4; ++n) acc[n] = __builtin_amdgcn_mfma_f32_16x16x32_f16(A3, Wf[n][3], acc[n], 0, 0, 0);
    }

    // ---- K-split partials to LDS.  D layout: row(batch) = kq*4+j, col = sub-col.
#pragma unroll
    for (int n = 0; n < 4; ++n)
#pragma unroll
      for (int j = 0; j < 4; ++j)
        P[0][PIDX(wave, n, kq * 4 + j, col)] = acc[n][j];

    __syncthreads();   // barrier-1: partials complete

    // ---- reduce over 8 waves (paired reads) + input term + tanh
    float s_lo = 0.f, s_hi = 0.f;
#pragma unroll
    for (int w8 = 0; w8 < 8; ++w8) {
      f32x2 t = *(const f32x2*)&P[0][PIDX(w8, n_e, r, c0)];   // ds_read2_b32
      s_lo += t.x;
      s_hi += t.y;
    }
    float v_lo = fast_tanh(s_lo + u * win_lo);
    float v_hi = fast_tanh(s_hi + u * win_hi);

    const unsigned int tagw = (unsigned)((((s + 1) >> 1) + ((s + 1) & 1)) & 1);
    union { f16 h[2]; unsigned int u32; } pk;
    pk.h[0] = (f16)v_lo;
    pk.h[1] = (f16)v_hi;
    pk.u32  = (pk.u32 & ~1u) | tagw;   // tag in LSB of low fp16 only

    unsigned int* Hp = (unsigned int*)((s & 1) ? hp0 : hp1);
    // primary: plain write-back store -> dirty in local XCD L2 (fast path)
    Hp[houtidx] = pk.u32;
    if (!l2mode) {
      // unverified group: keep the write-through LLC mirror (fallback)
      unsigned int* Hm = (unsigned int*)((s & 1) ? hm0 : hm1);
      __hip_atomic_store(&Hm[houtidx], pk.u32, __ATOMIC_RELAXED,
                         __HIP_MEMORY_SCOPE_AGENT);
    }

    __syncthreads();   // barrier-2: store drain (vmcnt(0) before s_barrier) —
                       // this is the RELEASE for the flag store below.
    if (tid == 0) {
      // publish "h_{s+1} available": plain write-back store, lands in the
      // group's own XCD-L2 flag line. Monotonic -> stale reads only under-read.
      unsigned int fv = su + 1u;
      asm volatile("global_store_dword %0, %1, off"
                   :: "v"(fmine), "v"(fv) : "memory");
    }
  }
}

// out[b][d] = sum_k h[b][k] * Wout[d][k] + bout[d];  h fp16 from PRIMARY buffer 0
// (H_512, 512 even; kernel-end drain + inter-dispatch writeback publish dirty L2)
__global__ __launch_bounds__(256) void res_readout_kernel(
    const f16* __restrict__ Hf,       // [256][1024] fp16
    const float* __restrict__ Wout,   // [512][1024]
    const float* __restrict__ bout,   // [512]
    float* __restrict__ out)          // [256][512]
{
  __shared__ f16 hs[16][1032];
  __shared__ f16 wsh[32][1032];
  const int tid = threadIdx.x;
  const int bb = blockIdx.x >> 4;   // batch block (16 rows)
  const int db = blockIdx.x & 15;   // d block (32 cols)

  for (int idx = tid; idx < 2048; idx += 256) {
    int row = idx >> 7, cin = idx & 127;
    *(half8*)&hs[row][cin * 8] = *(const half8*)(Hf + (size_t)(bb * 16 + row) * RES + cin * 8);
  }
  for (int idx = tid; idx < 4096; idx += 256) {
    int row = idx >> 7, cin = idx & 127;
    const float* p = Wout + (size_t)(db * 32 + row) * RES + cin * 8;
    f32x4 lo = *(const f32x4*)(p);
    f32x4 hi = *(const f32x4*)(p + 4);
    half8 f;
#pragma unroll
    for (int j = 0; j < 4; ++j) { f[j] = (f16)lo[j]; f[j + 4] = (f16)hi[j]; }
    *(half8*)&wsh[row][cin * 8] = f;
  }
  __syncthreads();

  const int d  = tid & 31;
  const int bp = tid >> 5;
  float acc0 = 0.f, acc1 = 0.f;
  for (int kc = 0; kc < 128; ++kc) {
    half8 wv = *(const half8*)&wsh[d][kc * 8];
    half8 h0 = *(const half8*)&hs[bp * 2][kc * 8];
    half8 h1 = *(const half8*)&hs[bp * 2 + 1][kc * 8];
#pragma unroll
    for (int j = 0; j < 8; ++j) {
      float wf = (float)wv[j];
      acc0 += wf * (float)h0[j];
      acc1 += wf * (float)h1[j];
    }
  }
  float bo = bout[db * 32 + d];
  out[(size_t)(bb * 16 + bp * 2) * 512 + db * 32 + d]     = acc0 + bo;
  out[(size_t)(bb * 16 + bp * 2 + 1) * 512 + db * 32 + d] = acc1 + bo;
}

extern "C" void kernel_launch(void* const* d_in, const int* in_sizes, int n_in,
                              void* d_out, int out_size, void* d_ws, size_t ws_size,
                              hipStream_t stream) {
  (void)in_sizes; (void)n_in; (void)out_size; (void)ws_size;
  const float* x     = (const float*)d_in[0];
  const float* W_in  = (const float*)d_in[1];
  const float* W_res = (const float*)d_in[2];
  const float* Wout  = (const float*)d_in[3];
  const float* bout  = (const float*)d_in[4];
  float* out = (float*)d_out;

  char* ws = (char*)d_ws;
  f16* hp0 = (f16*)(ws);
  f16* hp1 = (f16*)(ws + (512u << 10));
  f16* hm0 = (f16*)(ws + (1024u << 10));
  f16* hm1 = (f16*)(ws + (1536u << 10));
  unsigned int* xcdmap = (unsigned int*)(ws + (2048u << 10));
  unsigned int* flags  = (unsigned int*)(ws + (2048u << 10) + 1024);

  // zero all four H buffers (tags: zeros = valid h0 / invalid first-write),
  // the xcdmap and the flags each launch — erases stale state from previous
  // graph replay (flags are monotonic within a launch, must restart at 0).
  hipMemsetAsync(ws, 0, (2048u << 10), stream);
  hipMemsetAsync(ws + (2048u << 10), 0, 2048, stream);

  res_recur_kernel<<<dim3(256), dim3(512), 0, stream>>>(x, W_in, W_res,
                                                        hp0, hp1, hm0, hm1,
                                                        xcdmap, flags);
  res_readout_kernel<<<dim3(256), dim3(256), 0, stream>>>(hp0, Wout, bout, out);
}

// Round 2
// 863.595 us; speedup vs baseline: 1.1160x; 1.1160x over previous
//
#include <hip/hip_runtime.h>

#define RES 1024
#define SEQ 512

typedef _Float16 f16;
typedef _Float16 half8 __attribute__((ext_vector_type(8)));
typedef float f32x4 __attribute__((ext_vector_type(4)));
typedef float f32x2 __attribute__((ext_vector_type(2), aligned(4)));
typedef unsigned int uint4v __attribute__((ext_vector_type(4)));

// LDS partial-sum layout [w8][n][r][c], odd row-stride 19 (round-5): both the
// MFMA partial-write set and the reduce-read set are exact 2-way (free, m136).
#define PSZ (8 * 4 * 16 * 19)
#define PIDX(w8, n, rr, cc) ((((w8) * 4 + (n)) * 16 + (rr)) * 19 + (cc))

// Workspace layout (memset 0 each launch):
//   [0   , 512K) : PRIMARY H buffer 0   (plain write-back stores -> local XCD L2)
//   [512K, 1M  ) : PRIMARY H buffer 1
//   [1M  , 1.5M) : MIRROR  H buffer 0   (write-through agent stores; ONLY used
//   [1.5M, 2M  ) : MIRROR  H buffer 1    by groups that fail the placement check)
//   [2M  , 2M+1K): xcdmap, uint[256]
//
// Grid: 256 wgs x 512 threads. wg -> (group g, slice w):
//   g = (bx&7)*2 + ((bx>>3)&1), w = bx>>4   (a group's 16 wgs share bx mod 16)
// Group g owns batch rows [g*16,g*16+16); wg w owns reservoir cols [w*64,w*64+64).
// Wave k consumes K-range [k*128,(k+1)*128) -> producers {2k,2k+1}.
//
// Round-16 = round-14 champion (865us; round-15's flag protocol REVERTED — it
// traded latency for traffic and regressed to 964us) with ONE change: barrier-2
// is a RAW s_barrier instead of __syncthreads(). __syncthreads emits
// `s_waitcnt vmcnt(0)` before s_barrier, which serializes the H-store's full
// L2 completion (~200-300cy) into every step's critical path. The protocol
// never needed that drain: correctness is carried by the tags (a consumer
// racing an in-flight store simply retries), and the LDS WAR across the
// barrier is safe because the reduce's ds_read data is consumed by the
// tanh/store dataflow BEFORE the barrier. The store instead drains in the
// shadow of the next step's load+MFMA phase (barrier-1's __syncthreads picks
// it up ~800cy later, by which time it is free). r13's lesson is respected:
// the alignment BARRIER stays — only the drain goes.

__device__ __forceinline__ float fast_tanh(float v) {
  float vc = fminf(15.0f, fmaxf(-15.0f, v));
  float e = __expf(2.0f * vc);
  return (e - 1.0f) * __builtin_amdgcn_rcpf(e + 1.0f);
}

#define FULL_LOAD(ptr)                                                  \
  asm volatile(                                                         \
      "global_load_dwordx4 %0, %4, off sc0 sc1\n\t"                     \
      "global_load_dwordx4 %1, %4, off offset:64 sc0 sc1\n\t"           \
      "global_load_dwordx4 %2, %4, off offset:128 sc0 sc1\n\t"          \
      "global_load_dwordx4 %3, %4, off offset:192 sc0 sc1\n\t"          \
      "s_waitcnt vmcnt(0)"                                              \
      : "=&v"(A0), "=&v"(A1), "=&v"(A2), "=&v"(A3) : "v"(ptr) : "memory")

__device__ __forceinline__ bool tags_ok(half8 A0, half8 A1, half8 A2, half8 A3,
                                        unsigned int tagr) {
  const uint4v b0 = __builtin_bit_cast(uint4v, A0);
  const uint4v b1 = __builtin_bit_cast(uint4v, A1);
  const uint4v b2 = __builtin_bit_cast(uint4v, A2);
  const uint4v b3 = __builtin_bit_cast(uint4v, A3);
  unsigned int d =
      (b0.x ^ tagr) | (b0.y ^ tagr) | (b0.z ^ tagr) | (b0.w ^ tagr) |
      (b1.x ^ tagr) | (b1.y ^ tagr) | (b1.z ^ tagr) | (b1.w ^ tagr) |
      (b2.x ^ tagr) | (b2.y ^ tagr) | (b2.z ^ tagr) | (b2.w ^ tagr) |
      (b3.x ^ tagr) | (b3.y ^ tagr) | (b3.z ^ tagr) | (b3.w ^ tagr);
  return ((d & 1u) == 0u);
}

__global__ __launch_bounds__(512, 2) void res_recur_kernel(
    const float* __restrict__ x,      // [256][512]
    const float* __restrict__ W_in,   // [1024]
    const float* __restrict__ W_res,  // [1024][1024]
    f16* __restrict__ hp0,            // primary buffers
    f16* __restrict__ hp1,
    f16* __restrict__ hm0,            // mirror buffers (fallback groups only)
    f16* __restrict__ hm1,
    unsigned int* __restrict__ xcdmap)
{
  // [2][PSZ+1024] = 86,016 B total: > 80 KB forces 1 wg/CU (the round-14 lever).
  // Only plane [0] is used; the second plane exists purely as LDS ballast that
  // the compiler cannot strip (single allocated object, dynamically indexed).
  __shared__ float P[2][PSZ + 1024];
  __shared__ unsigned char xmap_s[256];
  __shared__ int l2mode_s;

  const int tid  = threadIdx.x;
  const int wave = tid >> 6;
  const int lane = tid & 63;
  const int col  = lane & 15;
  const int kq   = (lane >> 4) & 3;

  const int bx = blockIdx.x;
  const int g  = (bx & 7) * 2 + ((bx >> 3) & 1);
  const int w  = bx >> 4;

  // ---- publish my XCC id (write-through agent store -> globally visible)
  unsigned int myxcc;
  asm volatile("s_getreg_b32 %0, hwreg(HW_REG_XCC_ID, 0, 8)" : "=s"(myxcc));
  if (tid == 0)
    __hip_atomic_store(&xcdmap[bx], (myxcc & 0xffu) + 1u, __ATOMIC_RELAXED,
                       __HIP_MEMORY_SCOPE_AGENT);

  // ---- W_res fragments (MFMA B operand), register-resident for the whole run.
  // Wf[n][ks] elem j = W_res[w*64+n*16+col][ wave*128 + ks*32 + kq*8 + j ]
  half8 Wf[4][4];
#pragma unroll
  for (int n = 0; n < 4; ++n) {
    const float* Wr = W_res + (size_t)(w * 64 + n * 16 + col) * RES + wave * 128 + kq * 8;
#pragma unroll
    for (int ks = 0; ks < 4; ++ks) {
      f32x4 lo = *(const f32x4*)(Wr + ks * 32);
      f32x4 hi = *(const f32x4*)(Wr + ks * 32 + 4);
      half8 f;
#pragma unroll
      for (int j = 0; j < 4; ++j) { f[j] = (f16)lo[j]; f[j + 4] = (f16)hi[j]; }
      Wf[n][ks] = f;
    }
  }

  // ---- gather all 256 XCC ids (coherent sc0 sc1 loads; 256 wgs on 256 CUs are
  // trivially co-resident at 1 wg/CU, so this terminates)
  if (tid < 256) {
    const unsigned int* ap = xcdmap + tid;
    unsigned int v;
    do {
      asm volatile("global_load_dword %0, %1, off sc0 sc1\n\t"
                   "s_waitcnt vmcnt(0)"
                   : "=&v"(v) : "v"(ap) : "memory");
    } while (v == 0u);
    xmap_s[tid] = (unsigned char)v;
  }
  __syncthreads();
  if (tid == 0) {
    const int base = (g >> 1) + 8 * (g & 1);   // bx of this group's w=0 member
    const unsigned char ref = xmap_s[base];
    int ok = 1, cnt = 0;
    for (int i = 0; i < 256; ++i) cnt += (xmap_s[i] == ref) ? 1 : 0;
    for (int k = 0; k < 16; ++k) ok &= (xmap_s[base + 16 * k] == ref) ? 1 : 0;
    l2mode_s = (ok && cnt <= 64) ? 1 : 0;
  }
  __syncthreads();
  const bool l2mode = (l2mode_s != 0);   // group-uniform by construction

  // ---- epilogue assignment: thread t -> (batch-row r, col pair) of the 16x64 tile
  const int r   = tid >> 5;            // 0..15
  const int cp  = tid & 31;            // col pair
  const int n_e = cp >> 3;             // n-tile 0..3
  const int c0  = (cp & 7) * 2;        // even col within tile
  const float win_lo = W_in[w * 64 + n_e * 16 + c0];
  const float win_hi = W_in[w * 64 + n_e * 16 + c0 + 1];
  const float* xr = x + (size_t)(g * 16 + r) * SEQ;
  const unsigned int houtidx = ((unsigned)(g * 16 + r) * RES + w * 64 + n_e * 16 + c0) >> 1;

  const size_t aoff = (size_t)(g * 16 + col) * RES + wave * 128 + kq * 8;

  for (int s = 0; s < SEQ; ++s) {
    float u = xr[s];

    f32x4 acc[4];
#pragma unroll
    for (int n = 0; n < 4; ++n) acc[n] = (f32x4){0.f, 0.f, 0.f, 0.f};

    if (s > 0) {
      const unsigned int tagr = (unsigned)(((s >> 1) + (s & 1)) & 1);
      const f16* Ap = ((s & 1) ? hp1 : hp0) + aoff;   // primary (same-XCD L2)
      const f16* Am = ((s & 1) ? hm1 : hm0) + aoff;   // mirror  (fallback)
      half8 A0, A1, A2, A3;

      // iteration 0: full load from primary
      FULL_LOAD(Ap);
      bool ok = tags_ok(A0, A1, A2, A3, tagr);
      unsigned int it = 0;
      while (!ok) {
        ++it;
        // verified groups never consult the mirror (never written there);
        // unverified groups take the every-8th-retry LLC fallback (round-6).
        const f16* Pp = (!l2mode && ((it & 7u) == 0u)) ? Am : Ap;
        FULL_LOAD(Pp);
        ok = tags_ok(A0, A1, A2, A3, tagr);
      }

#pragma unroll
      for (int n = 0; n < 4; ++n) acc[n] = __builtin_amdgcn_mfma_f32_16x16x32_f16(A0, Wf[n][0], acc[n], 0, 0, 0);
#pragma unroll
      for (int n = 0; n < 4; ++n) acc[n] = __builtin_amdgcn_mfma_f32_16x16x32_f16(A1, Wf[n][1], acc[n], 0, 0, 0);
#pragma unroll
      for (int n = 0; n < 4; ++n) acc[n] = __builtin_amdgcn_mfma_f32_16x16x32_f16(A2, Wf[n][2], acc[n], 0, 0, 0);
#pragma unroll
      for (int n = 0; n < 4; ++n) acc[n] = __builtin_amdgcn_mfma_f32_16x16x32_f16(A3, Wf[n][3], acc[n], 0, 0, 0);
    }

    // ---- K-split partials to LDS.  D layout: row(batch) = kq*4+j, col = sub-col.
#pragma unroll
    for (int n = 0; n < 4; ++n)
#pragma unroll
      for (int j = 0; j < 4; ++j)
        P[0][PIDX(wave, n, kq * 4 + j, col)] = acc[n][j];

    __syncthreads();   // barrier-1: partials complete (full drain; also mops up
                       // the previous step's H-store at zero cost — it has had
                       // the whole load+MFMA phase to complete)

    // ---- reduce over 8 waves (paired reads) + input term + tanh
    float s_lo = 0.f, s_hi = 0.f;
#pragma unroll
    for (int w8 = 0; w8 < 8; ++w8) {
      f32x2 t = *(const f32x2*)&P[0][PIDX(w8, n_e, r, c0)];   // ds_read2_b32
      s_lo += t.x;
      s_hi += t.y;
    }
    float v_lo = fast_tanh(s_lo + u * win_lo);
    float v_hi = fast_tanh(s_hi + u * win_hi);

    const unsigned int tagw = (unsigned)((((s + 1) >> 1) + ((s + 1) & 1)) & 1);
    union { f16 h[2]; unsigned int u32; } pk;
    pk.h[0] = (f16)v_lo;
    pk.h[1] = (f16)v_hi;
    pk.u32  = (pk.u32 & ~1u) | tagw;   // tag in LSB of low fp16 only

    unsigned int* Hp = (unsigned int*)((s & 1) ? hp0 : hp1);
    // primary: plain write-back store -> dirty in local XCD L2 (fast path)
    Hp[houtidx] = pk.u32;
    if (!l2mode) {
      // unverified group: keep the write-through LLC mirror (fallback)
      unsigned int* Hm = (unsigned int*)((s & 1) ? hm0 : hm1);
      __hip_atomic_store(&Hm[houtidx], pk.u32, __ATOMIC_RELAXED,
                         __HIP_MEMORY_SCOPE_AGENT);
    }

    // barrier-2: RAW s_barrier — alignment only, NO vmcnt drain (the r16 lever).
    // The H-store stays in flight; tags make any read-of-in-flight-data a
    // harmless retry. LDS WAR is safe: the reduce's ds_read data was consumed
    // by the tanh/store dataflow above, so the reads retired before this point.
    asm volatile("" ::: "memory");         // pin the store before the barrier
    __builtin_amdgcn_s_barrier();
  }
}

// out[b][d] = sum_k h[b][k] * Wout[d][k] + bout[d];  h fp16 from PRIMARY buffer 0
// (H_512, 512 even; kernel-end drain + inter-dispatch writeback publish dirty L2)
__global__ __launch_bounds__(256) void res_readout_kernel(
    const f16* __restrict__ Hf,       // [256][1024] fp16
    const float* __restrict__ Wout,   // [512][1024]
    const float* __restrict__ bout,   // [512]
    float* __restrict__ out)          // [256][512]
{
  __shared__ f16 hs[16][1032];
  __shared__ f16 wsh[32][1032];
  const int tid = threadIdx.x;
  const int bb = blockIdx.x >> 4;   // batch block (16 rows)
  const int db = blockIdx.x & 15;   // d block (32 cols)

  for (int idx = tid; idx < 2048; idx += 256) {
    int row = idx >> 7, cin = idx & 127;
    *(half8*)&hs[row][cin * 8] = *(const half8*)(Hf + (size_t)(bb * 16 + row) * RES + cin * 8);
  }
  for (int idx = tid; idx < 4096; idx += 256) {
    int row = idx >> 7, cin = idx & 127;
    const float* p = Wout + (size_t)(db * 32 + row) * RES + cin * 8;
    f32x4 lo = *(const f32x4*)(p);
    f32x4 hi = *(const f32x4*)(p + 4);
    half8 f;
#pragma unroll
    for (int j = 0; j < 4; ++j) { f[j] = (f16)lo[j]; f[j + 4] = (f16)hi[j]; }
    *(half8*)&wsh[row][cin * 8] = f;
  }
  __syncthreads();

  const int d  = tid & 31;
  const int bp = tid >> 5;
  float acc0 = 0.f, acc1 = 0.f;
  for (int kc = 0; kc < 128; ++kc) {
    half8 wv = *(const half8*)&wsh[d][kc * 8];
    half8 h0 = *(const half8*)&hs[bp * 2][kc * 8];
    half8 h1 = *(const half8*)&hs[bp * 2 + 1][kc * 8];
#pragma unroll
    for (int j = 0; j < 8; ++j) {
      float wf = (float)wv[j];
      acc0 += wf * (float)h0[j];
      acc1 += wf * (float)h1[j];
    }
  }
  float bo = bout[db * 32 + d];
  out[(size_t)(bb * 16 + bp * 2) * 512 + db * 32 + d]     = acc0 + bo;
  out[(size_t)(bb * 16 + bp * 2 + 1) * 512 + db * 32 + d] = acc1 + bo;
}

extern "C" void kernel_launch(void* const* d_in, const int* in_sizes, int n_in,
                              void* d_out, int out_size, void* d_ws, size_t ws_size,
                              hipStream_t stream) {
  (void)in_sizes; (void)n_in; (void)out_size; (void)ws_size;
  const float* x     = (const float*)d_in[0];
  const float* W_in  = (const float*)d_in[1];
  const float* W_res = (const float*)d_in[2];
  const float* Wout  = (const float*)d_in[3];
  const float* bout  = (const float*)d_in[4];
  float* out = (float*)d_out;

  char* ws = (char*)d_ws;
  f16* hp0 = (f16*)(ws);
  f16* hp1 = (f16*)(ws + (512u << 10));
  f16* hm0 = (f16*)(ws + (1024u << 10));
  f16* hm1 = (f16*)(ws + (1536u << 10));
  unsigned int* xcdmap = (unsigned int*)(ws + (2048u << 10));

  // zero all four H buffers (tags: zeros = valid h0 / invalid first-write) and
  // the xcdmap each launch — erases stale state from previous graph replay.
  hipMemsetAsync(ws, 0, (2048u << 10), stream);
  hipMemsetAsync(ws + (2048u << 10), 0, 1024, stream);

  res_recur_kernel<<<dim3(256), dim3(512), 0, stream>>>(x, W_in, W_res,
                                                        hp0, hp1, hm0, hm1, xcdmap);
  res_readout_kernel<<<dim3(256), dim3(256), 0, stream>>>(hp0, Wout, bout, out);
}